// Round 7
// baseline (4085.224 us; speedup 1.0000x reference)
//
#include <hip/hip_runtime.h>

#define NSEG 63

typedef float    f32x4  __attribute__((ext_vector_type(4)));
typedef _Float16 half8  __attribute__((ext_vector_type(8)));
typedef _Float16 half4v __attribute__((ext_vector_type(4)));

#define W2_ELEMS 524288
#define W1_ELEMS 16384
#define W1H_OFF (2*W2_ELEMS)
#define W1L_OFF (W1H_OFF + W1_ELEMS)
#define B2_OFF  (W1L_OFF + W1_ELEMS)

__device__ __forceinline__ float fast_tanh(float x){
  float e = __builtin_amdgcn_exp2f(x * 2.885390081777927f); // 2*log2(e)
  float r = __builtin_amdgcn_rcpf(e + 1.0f);
  return fmaf(-2.0f, r, 1.0f);
}

__device__ __forceinline__ f32x4 sp4(float v){ f32x4 o = {v,v,v,v}; return o; }

__global__ __launch_bounds__(256) void prep_kernel(const float* __restrict__ W1,
                                                   const float* __restrict__ W2,
                                                   const float* __restrict__ b2,
                                                   _Float16* __restrict__ ws){
  int idx = blockIdx.x*256 + threadIdx.x;
  if (idx < W2_ELEMS){
    int m = idx >> 12, col = idx & 4095;       // W2[m][col], col = h*32+i
    int h = col >> 5,  i = col & 31;
    int kt = m >> 5,   kk = m & 31;
    int np = i*128 + h;
    float w = W2[idx];
    _Float16 hi = (_Float16)w;                 // fp16-hi only
    int pos = (kt*4096 + np)*32 + kk;
    ws[pos] = hi;
  } else if (idx < W2_ELEMS + W1_ELEMS){
    int j = idx - W2_ELEMS;
    int m = j >> 7, n = j & 127;               // W1[m][n]
    float w = W1[j];
    _Float16 hi = (_Float16)w;
    _Float16 lo = (_Float16)(w - (float)hi);
    int pos = ((m>>5)*128 + n)*32 + (m&31);
    ws[W1H_OFF + pos] = hi;
    ws[W1L_OFF + pos] = lo;
  } else if (idx < W2_ELEMS + W1_ELEMS + 4096){
    int j = idx - (W2_ELEMS + W1_ELEMS);       // b2[h*32+i]
    float* b2p = (float*)(ws + B2_OFF);
    b2p[(j & 31)*128 + (j >> 5)] = b2[j];
  }
}

// 128 WGs x 512 threads x 16 rows. 1 M-tile per wave, register z-state,
// 2 barriers/substep, depth-4 register-prefetched W2 B-fragments (nt loads).
__global__ __launch_bounds__(512)
__attribute__((amdgpu_waves_per_eu(2, 2)))
void cde_kernel(
    const float* __restrict__ coeffs,
    const float* __restrict__ W_init, const float* __restrict__ b_init,
    const float* __restrict__ b1,
    const float* __restrict__ W_ro,  const float* __restrict__ b_ro,
    const float* __restrict__ We1,   const float* __restrict__ be1,
    const float* __restrict__ We2,   const float* __restrict__ be2,
    const _Float16* __restrict__ wsw,
    float* __restrict__ out)
{
  __shared__ __align__(16) _Float16 Zs[16][136];  // stage-z hi (A of GEMM1)
  __shared__ __align__(16) _Float16 Zl[16][136];  // stage-z lo
  __shared__ __align__(16) _Float16 Hs[16][136];  // H hi (A of GEMM2)
  __shared__ __align__(16) _Float16 Hl[16][136];  // H lo
  __shared__ __align__(16) float dXT[3][32][16];  // dX variants [var][i][row]
  __shared__ __align__(16) float zfb[16][128];    // z0 init + final readout
  __shared__ __align__(16) float ylds[16][32];    // evolve stage y
  __shared__ __align__(16) float b2L[4096];       // permuted b2; reused as evolve tmp

  const int tid  = threadIdx.x;
  const int wave = tid >> 6;          // 0..7
  const int lane = tid & 63;
  const int q    = lane >> 4;
  const int ln16 = lane & 15;
  const int row4 = q * 4;
  const int bg   = blockIdx.x * 16;
  const int n0   = wave * 16;

  // ---- stage b2p into LDS ----
  {
    const float* b2p = (const float*)(wsw + B2_OFF);
    #pragma unroll
    for (int j = 0; j < 8; ++j) b2L[tid + j*512] = b2p[tid + j*512];
  }
  // ---- stage X0 = a[:,0] into dXT[0][i][r] ----
  {
    int r = tid >> 5, i = tid & 31;
    dXT[0][i][r] = coeffs[(size_t)(bg + r)*(NSEG*128) + i];
  }
  __syncthreads();

  // ---- z0 = X0 @ W_init + b_init (fp32) -> zfb + Zs/Zl ----
  {
    int r = tid >> 5, h0 = (tid & 31) * 4;
    f32x4 acc = *(const f32x4*)&b_init[h0];
    #pragma unroll 8
    for (int i = 0; i < 32; ++i)
      acc += sp4(dXT[0][i][r]) * (*(const f32x4*)&W_init[i*128 + h0]);
    *(f32x4*)&zfb[r][h0] = acc;
    half4v zh, zl;
    #pragma unroll
    for (int k = 0; k < 4; ++k){
      _Float16 hi = (_Float16)acc[k];
      zh[k] = hi; zl[k] = (_Float16)(acc[k] - (float)hi);
    }
    *(half4v*)&Zs[r][h0] = zh;
    *(half4v*)&Zl[r][h0] = zl;
  }

  // per-wave W1 fragments (persist in regs)
  half8 w1h[4], w1l[4];
  {
    const half8* W1h8 = (const half8*)(wsw + W1H_OFF);
    const half8* W1l8 = (const half8*)(wsw + W1L_OFF);
    #pragma unroll
    for (int kt = 0; kt < 4; ++kt){
      int fi = (kt*128 + n0 + ln16)*4 + q;
      w1h[kt] = W1h8[fi];
      w1l[kt] = W1l8[fi];
    }
  }
  const float b1v = b1[n0 + ln16];
  const half8* Bh8 = (const half8*)wsw;
  const int base8 = (n0 + ln16)*4 + q;
  __syncthreads();

  // ---- register z-state for owned fragment ----
  f32x4 zb, za = sp4(0.0f);
  #pragma unroll
  for (int k = 0; k < 4; ++k)
    zb[k] = zfb[row4 + k][n0 + ln16];

  // B-fragment loader: 4 hi-plane frags (kt 0..3), nontemporal (skip L1)
  auto loadB = [&](half8* bf, int i){
    bf[0] = __builtin_nontemporal_load(Bh8 + base8 +             i*512);
    bf[1] = __builtin_nontemporal_load(Bh8 + base8 +   16384 +   i*512);
    bf[2] = __builtin_nontemporal_load(Bh8 + base8 + 2*16384 +   i*512);
    bf[3] = __builtin_nontemporal_load(Bh8 + base8 + 3*16384 +   i*512);
  };

  // ================= CDE RK4 scan =================
  for (int t = 0; t < NSEG; ++t){
    // stage dX variants (readers are in phase B, after barrier 1)
    {
      int r = tid >> 5, i = tid & 31;
      const float* base = coeffs + (size_t)(bg + r)*(NSEG*128) + (size_t)t*128;
      float bb = base[32+i], cc = base[64+i], dd = base[96+i];
      dXT[0][i][r] = bb;
      dXT[1][i][r] = bb + cc + 0.75f*dd;
      float d4;
      if (t < NSEG-1) d4 = base[128+32+i];
      else            d4 = bb + 2.0f*cc + 3.0f*dd;
      dXT[2][i][r] = d4;
    }

    #pragma unroll 1
    for (int s = 0; s < 4; ++s){
      // prefetch first four W2 B-fragment sets (independent of this step's work)
      half8 bA[4], bB[4], bC[4], bD[4];
      loadB(bA, 0);
      loadB(bB, 1);
      loadB(bC, 2);
      loadB(bD, 3);

      // ---- Phase A: GEMM1: H = relu(Z @ W1 + b1), split-fp16 ----
      {
        half8 a1h[4], a1l[4];
        #pragma unroll
        for (int kt = 0; kt < 4; ++kt){
          a1h[kt] = *(const half8*)&Zs[ln16][kt*32 + q*8];
          a1l[kt] = *(const half8*)&Zl[ln16][kt*32 + q*8];
        }
        f32x4 u0 = sp4(b1v), u1 = sp4(0.0f), u2 = sp4(0.0f);
        #pragma unroll
        for (int kt = 0; kt < 4; ++kt){
          u0 = __builtin_amdgcn_mfma_f32_16x16x32_f16(a1h[kt], w1h[kt], u0, 0, 0, 0);
          u1 = __builtin_amdgcn_mfma_f32_16x16x32_f16(a1l[kt], w1h[kt], u1, 0, 0, 0);
          u2 = __builtin_amdgcn_mfma_f32_16x16x32_f16(a1h[kt], w1l[kt], u2, 0, 0, 0);
        }
        #pragma unroll
        for (int r = 0; r < 4; ++r){
          float hv = u0[r] + u1[r] + u2[r];
          hv = hv > 0.0f ? hv : 0.0f;
          _Float16 hi = (_Float16)hv;
          Hs[row4 + r][n0 + ln16] = hi;
          Hl[row4 + r][n0 + ln16] = (_Float16)(hv - (float)hi);
        }
      }
      __syncthreads();

      // ---- Phase B: GEMM2 + tanh + dX contraction, depth-4 prefetch ----
      half8 a2h[4], a2l[4];
      #pragma unroll
      for (int kt = 0; kt < 4; ++kt){
        a2h[kt] = *(const half8*)&Hs[ln16][kt*32 + q*8];
        a2l[kt] = *(const half8*)&Hl[ln16][kt*32 + q*8];
      }
      const int v = (s == 0) ? 0 : ((s == 3) ? 2 : 1);
      f32x4 dz = sp4(0.0f);

      auto body = [&](const half8* bf, int i){
        float b2v = b2L[i*128 + n0 + ln16];
        f32x4 u0 = sp4(b2v), u1 = sp4(0.0f);
        u0 = __builtin_amdgcn_mfma_f32_16x16x32_f16(a2h[0], bf[0], u0, 0, 0, 0);
        u1 = __builtin_amdgcn_mfma_f32_16x16x32_f16(a2l[0], bf[0], u1, 0, 0, 0);
        u0 = __builtin_amdgcn_mfma_f32_16x16x32_f16(a2h[1], bf[1], u0, 0, 0, 0);
        u1 = __builtin_amdgcn_mfma_f32_16x16x32_f16(a2l[1], bf[1], u1, 0, 0, 0);
        u0 = __builtin_amdgcn_mfma_f32_16x16x32_f16(a2h[2], bf[2], u0, 0, 0, 0);
        u1 = __builtin_amdgcn_mfma_f32_16x16x32_f16(a2l[2], bf[2], u1, 0, 0, 0);
        u0 = __builtin_amdgcn_mfma_f32_16x16x32_f16(a2h[3], bf[3], u0, 0, 0, 0);
        u1 = __builtin_amdgcn_mfma_f32_16x16x32_f16(a2l[3], bf[3], u1, 0, 0, 0);
        f32x4 dxv = *(const f32x4*)&dXT[v][i][row4];
        #pragma unroll
        for (int r = 0; r < 4; ++r)
          dz[r] = fmaf(fast_tanh(u0[r] + u1[r]), dxv[r], dz[r]);
      };

      for (int ii = 0; ii < 28; ii += 4){
        body(bA, ii);     loadB(bA, ii + 4);
        body(bB, ii + 1); loadB(bB, ii + 5);
        body(bC, ii + 2); loadB(bC, ii + 6);
        body(bD, ii + 3); loadB(bD, ii + 7);
      }
      body(bA, 28);
      body(bB, 29);
      body(bC, 30);
      body(bD, 31);

      // ---- in-register RK4 update + Zs/Zl write ----
      const float wk = (s == 3) ? 1.0f : 2.0f;
      #pragma unroll
      for (int k = 0; k < 4; ++k){
        float zan = (s == 0) ? dz[k] : za[k] + wk*dz[k];
        za[k] = zan;
        float zs;
        if (s == 3){ zb[k] += zan*(1.0f/6.0f); zs = zb[k]; }
        else if (s == 2) zs = zb[k] + dz[k];
        else             zs = zb[k] + 0.5f*dz[k];
        _Float16 hi = (_Float16)zs;
        Zs[row4 + k][n0 + ln16] = hi;
        Zl[row4 + k][n0 + ln16] = (_Float16)(zs - (float)hi);
      }
      __syncthreads();
    }
  }

  // ---- write final z back to zfb for readout ----
  #pragma unroll
  for (int k = 0; k < 4; ++k)
    zfb[row4 + k][n0 + ln16] = zb[k];
  __syncthreads();

  // ================= readout + evolve head (fp32) =================
  const int r = tid >> 5, c = tid & 31;
  float yb = 0.0f, yac = 0.0f;
  {
    float yv = b_ro[c];
    #pragma unroll 8
    for (int h = 0; h < 128; ++h)
      yv = fmaf(zfb[r][h], W_ro[h*32 + c], yv);
    ylds[r][c] = yv;
    yb = yv;
  }
  __syncthreads();

  for (int st = 0; st < 10; ++st){
    #pragma unroll 1
    for (int s = 0; s < 4; ++s){
      // tmp = tanh(ys @ We1 + be1) -> b2L (reused as [16][128])
      {
        int rr = tid >> 5, m0 = (tid & 31) * 4;
        f32x4 acc = *(const f32x4*)&be1[m0];
        #pragma unroll 4
        for (int i = 0; i < 32; ++i)
          acc += sp4(ylds[rr][i]) * (*(const f32x4*)&We1[i*128 + m0]);
        f32x4 tt;
        tt.x = fast_tanh(acc.x); tt.y = fast_tanh(acc.y);
        tt.z = fast_tanh(acc.z); tt.w = fast_tanh(acc.w);
        *(f32x4*)&b2L[rr*128 + m0] = tt;
      }
      __syncthreads();
      {
        float kv = be2[c];
        #pragma unroll 8
        for (int m = 0; m < 128; ++m)
          kv = fmaf(b2L[r*128 + m], We2[m*32 + c], kv);
        float ysn;
        if      (s == 0){ yac = kv;        ysn = yb + 0.25f*kv; }
        else if (s == 1){ yac += 2.0f*kv;  ysn = yb + 0.25f*kv; }
        else if (s == 2){ yac += 2.0f*kv;  ysn = yb + 0.5f*kv;  }
        else            { yac += kv;       yb += yac*(1.0f/12.0f); ysn = yb; }
        ylds[r][c] = ysn;
      }
      __syncthreads();
    }
  }
  out[(size_t)(bg + r)*32 + c] = yb;
}

extern "C" void kernel_launch(void* const* d_in, const int* in_sizes, int n_in,
                              void* d_out, int out_size, void* d_ws, size_t ws_size,
                              hipStream_t stream){
  const float* coeffs = (const float*)d_in[0];
  const float* W_init = (const float*)d_in[1];
  const float* b_init = (const float*)d_in[2];
  const float* W1     = (const float*)d_in[3];
  const float* b1     = (const float*)d_in[4];
  const float* W2     = (const float*)d_in[5];
  const float* b2     = (const float*)d_in[6];
  const float* W_ro   = (const float*)d_in[7];
  const float* b_ro   = (const float*)d_in[8];
  const float* We1    = (const float*)d_in[9];
  const float* be1    = (const float*)d_in[10];
  const float* We2    = (const float*)d_in[11];
  const float* be2    = (const float*)d_in[12];
  _Float16* ws        = (_Float16*)d_ws;

  prep_kernel<<<2128, 256, 0, stream>>>(W1, W2, b2, ws);
  cde_kernel<<<128, 512, 0, stream>>>(coeffs, W_init, b_init, b1, W_ro, b_ro,
                                      We1, be1, We2, be2, ws, (float*)d_out);
}

// Round 8
// 3139.223 us; speedup vs baseline: 1.3013x; 1.3013x over previous
//
#include <hip/hip_runtime.h>

#define NSEG 63

typedef float    f32x4  __attribute__((ext_vector_type(4)));
typedef _Float16 half8  __attribute__((ext_vector_type(8)));
typedef _Float16 half4v __attribute__((ext_vector_type(4)));

#define W2_ELEMS 524288
#define W1_ELEMS 16384
#define W1H_OFF (2*W2_ELEMS)
#define W1L_OFF (W1H_OFF + W1_ELEMS)
#define B2_OFF  (W1L_OFF + W1_ELEMS)

__device__ __forceinline__ float fast_tanh(float x){
  float e = __builtin_amdgcn_exp2f(x * 2.885390081777927f); // 2*log2(e)
  float r = __builtin_amdgcn_rcpf(e + 1.0f);
  return fmaf(-2.0f, r, 1.0f);
}

__device__ __forceinline__ f32x4 sp4(float v){ f32x4 o = {v,v,v,v}; return o; }

// async global->LDS DMA, 16B per lane: lane i writes lds_base + i*16
__device__ __forceinline__ void dma16(const _Float16* g, _Float16* l){
  __builtin_amdgcn_global_load_lds(
      (const __attribute__((address_space(1))) unsigned int*)g,
      (__attribute__((address_space(3))) unsigned int*)l,
      16, 0, 0);
}

__global__ __launch_bounds__(256) void prep_kernel(const float* __restrict__ W1,
                                                   const float* __restrict__ W2,
                                                   const float* __restrict__ b2,
                                                   _Float16* __restrict__ ws){
  int idx = blockIdx.x*256 + threadIdx.x;
  if (idx < W2_ELEMS){
    int m = idx >> 12, col = idx & 4095;       // W2[m][col], col = h*32+i
    int h = col >> 5,  i = col & 31;
    int kt = m >> 5,   kk = m & 31;
    int np = i*128 + h;
    float w = W2[idx];
    _Float16 hi = (_Float16)w;                 // fp16-hi only
    int pos = (kt*4096 + np)*32 + kk;
    ws[pos] = hi;
  } else if (idx < W2_ELEMS + W1_ELEMS){
    int j = idx - W2_ELEMS;
    int m = j >> 7, n = j & 127;               // W1[m][n]
    float w = W1[j];
    _Float16 hi = (_Float16)w;
    _Float16 lo = (_Float16)(w - (float)hi);
    int pos = ((m>>5)*128 + n)*32 + (m&31);
    ws[W1H_OFF + pos] = hi;
    ws[W1L_OFF + pos] = lo;
  } else if (idx < W2_ELEMS + W1_ELEMS + 4096){
    int j = idx - (W2_ELEMS + W1_ELEMS);       // b2[h*32+i]
    float* b2p = (float*)(ws + B2_OFF);
    b2p[(j & 31)*128 + (j >> 5)] = b2[j];
  }
}

// 128 WGs x 512 threads x 16 rows. W2 streamed via async global_load_lds into
// 3 rotating per-wave-private LDS buffers; hand s_waitcnt vmcnt(N) pipeline.
__global__ __launch_bounds__(512) void cde_kernel(
    const float* __restrict__ coeffs,
    const float* __restrict__ W_init, const float* __restrict__ b_init,
    const float* __restrict__ b1,
    const float* __restrict__ W_ro,  const float* __restrict__ b_ro,
    const float* __restrict__ We1,   const float* __restrict__ be1,
    const float* __restrict__ We2,   const float* __restrict__ be2,
    const _Float16* __restrict__ wsw,
    float* __restrict__ out)
{
  __shared__ __align__(16) _Float16 W2L[3][8][4][512]; // [buf][wave][kt][16colsx32k] 96KB
  __shared__ __align__(16) _Float16 Zs[16][136];  // stage-z hi (A of GEMM1)
  __shared__ __align__(16) _Float16 Zl[16][136];  // stage-z lo
  __shared__ __align__(16) _Float16 Hs[16][136];  // H hi (A of GEMM2)
  __shared__ __align__(16) _Float16 Hl[16][136];  // H lo
  __shared__ __align__(16) float dXT[3][32][16];  // dX variants [var][i][row]
  __shared__ __align__(16) float zfb[16][128];    // z0 init + final readout
  __shared__ __align__(16) float ylds[16][32];    // evolve stage y
  __shared__ __align__(16) float b2L[4096];       // permuted b2; reused as evolve tmp

  const int tid  = threadIdx.x;
  const int wave = tid >> 6;          // 0..7
  const int lane = tid & 63;
  const int q    = lane >> 4;
  const int ln16 = lane & 15;
  const int row4 = q * 4;
  const int bg   = blockIdx.x * 16;
  const int n0   = wave * 16;
  const int fo   = ln16*32 + q*8;     // B-frag offset within a 1KB kt-block

  // ---- stage b2p into LDS ----
  {
    const float* b2p = (const float*)(wsw + B2_OFF);
    #pragma unroll
    for (int j = 0; j < 8; ++j) b2L[tid + j*512] = b2p[tid + j*512];
  }
  // ---- stage X0 = a[:,0] into dXT[0][i][r] ----
  {
    int r = tid >> 5, i = tid & 31;
    dXT[0][i][r] = coeffs[(size_t)(bg + r)*(NSEG*128) + i];
  }
  __syncthreads();

  // ---- z0 = X0 @ W_init + b_init (fp32) -> zfb + Zs/Zl ----
  {
    int r = tid >> 5, h0 = (tid & 31) * 4;
    f32x4 acc = *(const f32x4*)&b_init[h0];
    #pragma unroll 8
    for (int i = 0; i < 32; ++i)
      acc += sp4(dXT[0][i][r]) * (*(const f32x4*)&W_init[i*128 + h0]);
    *(f32x4*)&zfb[r][h0] = acc;
    half4v zh, zl;
    #pragma unroll
    for (int k = 0; k < 4; ++k){
      _Float16 hi = (_Float16)acc[k];
      zh[k] = hi; zl[k] = (_Float16)(acc[k] - (float)hi);
    }
    *(half4v*)&Zs[r][h0] = zh;
    *(half4v*)&Zl[r][h0] = zl;
  }

  // per-wave W1 fragments (persist in regs)
  half8 w1h[4], w1l[4];
  {
    const half8* W1h8 = (const half8*)(wsw + W1H_OFF);
    const half8* W1l8 = (const half8*)(wsw + W1L_OFF);
    #pragma unroll
    for (int kt = 0; kt < 4; ++kt){
      int fi = (kt*128 + n0 + ln16)*4 + q;
      w1h[kt] = W1h8[fi];
      w1l[kt] = W1l8[fi];
    }
  }
  const float b1v = b1[n0 + ln16];
  __syncthreads();

  // ---- register z-state for owned fragment ----
  f32x4 zb, za = sp4(0.0f);
  #pragma unroll
  for (int k = 0; k < 4; ++k)
    zb[k] = zfb[row4 + k][n0 + ln16];

  // DMA one i-chunk (this wave's n-slice, 4 kt x 1KB) into buffer b
  auto issue = [&](int i, int b){
    const _Float16* g = wsw + (i*128 + n0)*32 + lane*8;
    _Float16* l = &W2L[b][wave][0][0];
    #pragma unroll
    for (int kt = 0; kt < 4; ++kt)
      dma16(g + kt*131072, l + kt*512);
  };

  // ================= CDE RK4 scan =================
  for (int t = 0; t < NSEG; ++t){
    // stage dX variants (readers are in phase B, after barrier 1)
    {
      int r = tid >> 5, i = tid & 31;
      const float* base = coeffs + (size_t)(bg + r)*(NSEG*128) + (size_t)t*128;
      float bb = base[32+i], cc = base[64+i], dd = base[96+i];
      dXT[0][i][r] = bb;
      dXT[1][i][r] = bb + cc + 0.75f*dd;
      float d4;
      if (t < NSEG-1) d4 = base[128+32+i];
      else            d4 = bb + 2.0f*cc + 3.0f*dd;
      dXT[2][i][r] = d4;
    }

    #pragma unroll 1
    for (int s = 0; s < 4; ++s){
      // prologue: start DMA of chunks 0..2 (latency covered by Phase A)
      issue(0, 0); issue(1, 1); issue(2, 2);

      // ---- Phase A: GEMM1: H = relu(Z @ W1 + b1), split-fp16 ----
      {
        half8 a1h[4], a1l[4];
        #pragma unroll
        for (int kt = 0; kt < 4; ++kt){
          a1h[kt] = *(const half8*)&Zs[ln16][kt*32 + q*8];
          a1l[kt] = *(const half8*)&Zl[ln16][kt*32 + q*8];
        }
        f32x4 u0 = sp4(b1v), u1 = sp4(0.0f), u2 = sp4(0.0f);
        #pragma unroll
        for (int kt = 0; kt < 4; ++kt){
          u0 = __builtin_amdgcn_mfma_f32_16x16x32_f16(a1h[kt], w1h[kt], u0, 0, 0, 0);
          u1 = __builtin_amdgcn_mfma_f32_16x16x32_f16(a1l[kt], w1h[kt], u1, 0, 0, 0);
          u2 = __builtin_amdgcn_mfma_f32_16x16x32_f16(a1h[kt], w1l[kt], u2, 0, 0, 0);
        }
        #pragma unroll
        for (int r = 0; r < 4; ++r){
          float hv = u0[r] + u1[r] + u2[r];
          hv = hv > 0.0f ? hv : 0.0f;
          _Float16 hi = (_Float16)hv;
          Hs[row4 + r][n0 + ln16] = hi;
          Hl[row4 + r][n0 + ln16] = (_Float16)(hv - (float)hi);
        }
      }
      __syncthreads();

      // ---- Phase B: GEMM2 + tanh + dX, LDS-DMA pipelined W2 ----
      half8 a2h[4], a2l[4];
      #pragma unroll
      for (int kt = 0; kt < 4; ++kt){
        a2h[kt] = *(const half8*)&Hs[ln16][kt*32 + q*8];
        a2l[kt] = *(const half8*)&Hl[ln16][kt*32 + q*8];
      }
      const int v = (s == 0) ? 0 : ((s == 3) ? 2 : 1);
      f32x4 dz = sp4(0.0f);

      auto body = [&](const _Float16* Wb, int i){
        float b2v = b2L[i*128 + n0 + ln16];
        half8 bf0 = *(const half8*)(Wb + fo);
        half8 bf1 = *(const half8*)(Wb +  512 + fo);
        half8 bf2 = *(const half8*)(Wb + 1024 + fo);
        half8 bf3 = *(const half8*)(Wb + 1536 + fo);
        f32x4 u0 = sp4(b2v), u1 = sp4(0.0f);
        u0 = __builtin_amdgcn_mfma_f32_16x16x32_f16(a2h[0], bf0, u0, 0, 0, 0);
        u1 = __builtin_amdgcn_mfma_f32_16x16x32_f16(a2l[0], bf0, u1, 0, 0, 0);
        u0 = __builtin_amdgcn_mfma_f32_16x16x32_f16(a2h[1], bf1, u0, 0, 0, 0);
        u1 = __builtin_amdgcn_mfma_f32_16x16x32_f16(a2l[1], bf1, u1, 0, 0, 0);
        u0 = __builtin_amdgcn_mfma_f32_16x16x32_f16(a2h[2], bf2, u0, 0, 0, 0);
        u1 = __builtin_amdgcn_mfma_f32_16x16x32_f16(a2l[2], bf2, u1, 0, 0, 0);
        u0 = __builtin_amdgcn_mfma_f32_16x16x32_f16(a2h[3], bf3, u0, 0, 0, 0);
        u1 = __builtin_amdgcn_mfma_f32_16x16x32_f16(a2l[3], bf3, u1, 0, 0, 0);
        f32x4 dxv = *(const f32x4*)&dXT[v][i][row4];
        #pragma unroll
        for (int r = 0; r < 4; ++r)
          dz[r] = fmaf(fast_tanh(u0[r] + u1[r]), dxv[r], dz[r]);
      };

      {
        int b = 0;
        #pragma unroll 1
        for (int i = 0; i < 30; ++i){
          asm volatile("s_waitcnt vmcnt(8)" ::: "memory");
          body(&W2L[b][wave][0][0], i);
          if (i <= 28) issue(i + 3, b);       // (i+3)%3 == i%3 == b
          b = (b == 2) ? 0 : b + 1;
        }
        asm volatile("s_waitcnt vmcnt(4)" ::: "memory");
        body(&W2L[0][wave][0][0], 30);        // 30 % 3 == 0
        asm volatile("s_waitcnt vmcnt(0)" ::: "memory");
        body(&W2L[1][wave][0][0], 31);        // 31 % 3 == 1
      }

      // ---- in-register RK4 update + Zs/Zl write ----
      const float wk = (s == 3) ? 1.0f : 2.0f;
      #pragma unroll
      for (int k = 0; k < 4; ++k){
        float zan = (s == 0) ? dz[k] : za[k] + wk*dz[k];
        za[k] = zan;
        float zs;
        if (s == 3){ zb[k] += zan*(1.0f/6.0f); zs = zb[k]; }
        else if (s == 2) zs = zb[k] + dz[k];
        else             zs = zb[k] + 0.5f*dz[k];
        _Float16 hi = (_Float16)zs;
        Zs[row4 + k][n0 + ln16] = hi;
        Zl[row4 + k][n0 + ln16] = (_Float16)(zs - (float)hi);
      }
      __syncthreads();
    }
  }

  // ---- write final z back to zfb for readout ----
  #pragma unroll
  for (int k = 0; k < 4; ++k)
    zfb[row4 + k][n0 + ln16] = zb[k];
  __syncthreads();

  // ================= readout + evolve head (fp32) =================
  const int r = tid >> 5, c = tid & 31;
  float yb = 0.0f, yac = 0.0f;
  {
    float yv = b_ro[c];
    #pragma unroll 8
    for (int h = 0; h < 128; ++h)
      yv = fmaf(zfb[r][h], W_ro[h*32 + c], yv);
    ylds[r][c] = yv;
    yb = yv;
  }
  __syncthreads();

  for (int st = 0; st < 10; ++st){
    #pragma unroll 1
    for (int s = 0; s < 4; ++s){
      // tmp = tanh(ys @ We1 + be1) -> b2L (reused as [16][128])
      {
        int rr = tid >> 5, m0 = (tid & 31) * 4;
        f32x4 acc = *(const f32x4*)&be1[m0];
        #pragma unroll 4
        for (int i = 0; i < 32; ++i)
          acc += sp4(ylds[rr][i]) * (*(const f32x4*)&We1[i*128 + m0]);
        f32x4 tt;
        tt.x = fast_tanh(acc.x); tt.y = fast_tanh(acc.y);
        tt.z = fast_tanh(acc.z); tt.w = fast_tanh(acc.w);
        *(f32x4*)&b2L[rr*128 + m0] = tt;
      }
      __syncthreads();
      {
        float kv = be2[c];
        #pragma unroll 8
        for (int m = 0; m < 128; ++m)
          kv = fmaf(b2L[r*128 + m], We2[m*32 + c], kv);
        float ysn;
        if      (s == 0){ yac = kv;        ysn = yb + 0.25f*kv; }
        else if (s == 1){ yac += 2.0f*kv;  ysn = yb + 0.25f*kv; }
        else if (s == 2){ yac += 2.0f*kv;  ysn = yb + 0.5f*kv;  }
        else            { yac += kv;       yb += yac*(1.0f/12.0f); ysn = yb; }
        ylds[r][c] = ysn;
      }
      __syncthreads();
    }
  }
  out[(size_t)(bg + r)*32 + c] = yb;
}

extern "C" void kernel_launch(void* const* d_in, const int* in_sizes, int n_in,
                              void* d_out, int out_size, void* d_ws, size_t ws_size,
                              hipStream_t stream){
  const float* coeffs = (const float*)d_in[0];
  const float* W_init = (const float*)d_in[1];
  const float* b_init = (const float*)d_in[2];
  const float* W1     = (const float*)d_in[3];
  const float* b1     = (const float*)d_in[4];
  const float* W2     = (const float*)d_in[5];
  const float* b2     = (const float*)d_in[6];
  const float* W_ro   = (const float*)d_in[7];
  const float* b_ro   = (const float*)d_in[8];
  const float* We1    = (const float*)d_in[9];
  const float* be1    = (const float*)d_in[10];
  const float* We2    = (const float*)d_in[11];
  const float* be2    = (const float*)d_in[12];
  _Float16* ws        = (_Float16*)d_ws;

  prep_kernel<<<2128, 256, 0, stream>>>(W1, W2, b2, ws);
  cde_kernel<<<128, 512, 0, stream>>>(coeffs, W_init, b_init, b1, W_ro, b_ro,
                                      We1, be1, We2, be2, ws, (float*)d_out);
}